// Round 8
// baseline (434.495 us; speedup 1.0000x reference)
//
#include <hip/hip_runtime.h>

#define HID 128

typedef unsigned short ushort_t;
typedef unsigned int uint_t;
typedef float f32x4 __attribute__((ext_vector_type(4)));
typedef short s16x8 __attribute__((ext_vector_type(8)));

__device__ __forceinline__ ushort_t f2bf(float f) {
  uint_t u = __float_as_uint(f);
  uint_t r = (u + 0x7FFFu + ((u >> 16) & 1u)) >> 16;  // RNE
  return (ushort_t)r;
}
__device__ __forceinline__ float bfLo(uint_t v) { return __uint_as_float(v << 16); }
__device__ __forceinline__ float bfHi(uint_t v) { return __uint_as_float(v & 0xFFFF0000u); }

// ------- fused prep: wide gather + weight-swizzle + degree count -------
// Ranges: [0, N*16) gather (16 thr/row, 2 indep float4 loads + uint4 store);
// [N*16, +65536) weight swizzle to MFMA B-frag order; then E degcount.
__global__ __launch_bounds__(256) void prep_kernel(
    const float* __restrict__ emb, const int* __restrict__ x,
    ushort_t* __restrict__ hb, int N,
    const float* __restrict__ Wl1, const float* __restrict__ Wr1,
    const float* __restrict__ Wl2, const float* __restrict__ Wr2,
    ushort_t* __restrict__ wsw,
    const int* __restrict__ dst, int* __restrict__ deg, int E) {
  int tid = blockIdx.x * 256 + threadIdx.x;
  int gthreads = N * 16;
  if (tid < gthreads) {
    int r = tid >> 4, j = (tid & 15) * 8;
    int s = x[r];
    const float* src = &emb[(size_t)s * HID + j];
    float4 v0 = *(const float4*)src;
    float4 v1 = *(const float4*)(src + 4);
    uint4 p;
    p.x = (uint_t)f2bf(v0.x) | ((uint_t)f2bf(v0.y) << 16);
    p.y = (uint_t)f2bf(v0.z) | ((uint_t)f2bf(v0.w) << 16);
    p.z = (uint_t)f2bf(v1.x) | ((uint_t)f2bf(v1.y) << 16);
    p.w = (uint_t)f2bf(v1.z) | ((uint_t)f2bf(v1.w) << 16);
    *(uint4*)&hb[(size_t)r * HID + j] = p;
    return;
  }
  tid -= gthreads;
  if (tid < 65536) {
    const float* srcs[4] = {Wl1, Wr1, Wl2, Wr2};
    int m = tid >> 14, idx = tid & 16383;
    int j = idx & 7;
    int lane = (idx >> 3) & 63;
    int nt = (idx >> 9) & 7;
    int ks = (idx >> 12) & 3;
    int row = nt * 16 + (lane & 15);
    int col = ks * 32 + (lane >> 4) * 8 + j;
    wsw[tid] = f2bf(srcs[m][row * HID + col]);
    return;
  }
  tid -= 65536;
  if (tid < E) atomicAdd(&deg[dst[tid]], 1);
}

// ---------------- CSR build ----------------
__global__ __launch_bounds__(256) void scan1_kernel(
    const int* __restrict__ deg, int* __restrict__ offsets,
    int* __restrict__ sums, int N) {
  __shared__ int s[256];
  int b = blockIdx.x, t = threadIdx.x;
  int base = b * 1024 + t * 4;
  int v0 = 0, v1 = 0, v2 = 0, v3 = 0;
  if (base + 0 < N) v0 = deg[base + 0];
  if (base + 1 < N) v1 = deg[base + 1];
  if (base + 2 < N) v2 = deg[base + 2];
  if (base + 3 < N) v3 = deg[base + 3];
  int mySum = v0 + v1 + v2 + v3;
  s[t] = mySum;
  __syncthreads();
  for (int off = 1; off < 256; off <<= 1) {
    int v = (t >= off) ? s[t - off] : 0;
    __syncthreads();
    s[t] += v;
    __syncthreads();
  }
  int excl = s[t] - mySum;
  if (t == 255) sums[b] = s[255];
  if (base + 0 < N) offsets[base + 0] = excl;
  if (base + 1 < N) offsets[base + 1] = excl + v0;
  if (base + 2 < N) offsets[base + 2] = excl + v0 + v1;
  if (base + 3 < N) offsets[base + 3] = excl + v0 + v1 + v2;
}

__global__ __launch_bounds__(256) void scan3_kernel(
    int* __restrict__ offsets, const int* __restrict__ sums,
    int* __restrict__ cursor, int N, int E, int nb) {
  __shared__ int red[256];
  int t = threadIdx.x;
  int chunk = (blockIdx.x * 256) >> 10;
  red[t] = (t < chunk) ? sums[t] : 0;
  __syncthreads();
  for (int off = 128; off > 0; off >>= 1) {
    if (t < off) red[t] += red[t + off];
    __syncthreads();
  }
  int prefix = red[0];
  int i = blockIdx.x * 256 + t;
  if (i < N) {
    int v = offsets[i] + prefix;
    offsets[i] = v;
    cursor[i] = v;
  } else if (i == N) {
    offsets[N] = E;
  }
}

__global__ __launch_bounds__(256) void fill_kernel(
    const int* __restrict__ src, const int* __restrict__ dst,
    int* __restrict__ cursor, int* __restrict__ csr, int E) {
  int e = blockIdx.x * 256 + threadIdx.x;
  if (e >= E) return;
  int d = dst[e];
  int pos = atomicAdd(&cursor[d], 1);
  csr[pos] = src[e];
}

// ------- fused layer: aggregate (into LDS) + MFMA transform -------
// Block = 4 waves x 32 rows. Per wave: aggregate each of its 32 nodes
// (quarter-wave edge split, 2-batched loads, f32 acc, bf16 round — identical
// numerics to the split version), store mean rows in an XOR-swizzled LDS tile
// (chunk^=row&7 -> A-frag ds_read_b128 spreads 8 lanes/bank-group = data
// floor). Weights staged 32 KB at a time (Wl phase1 / Wr phase2).
// h A-frags global-prefetched after aggregation, consumed in phase 2.
// NOT in-place: out must differ from hin (other blocks read all hin rows).
__global__ __launch_bounds__(256) void fused_layer_kernel(
    const ushort_t* __restrict__ hin, const int* __restrict__ offsets,
    const int* __restrict__ csr, const ushort_t* __restrict__ WlS,
    const ushort_t* __restrict__ WrS, const float* __restrict__ bias,
    float* __restrict__ outF, ushort_t* __restrict__ outB,
    int N, int outIsBf16) {
  __shared__ ushort_t ws[16384];     // 32 KB: one weight matrix (frag order)
  __shared__ ushort_t meanT[16384];  // 32 KB: 4 waves x 32 rows x 16 chunks(16B)
  const int t = threadIdx.x;
  const int wave = t >> 6;
  const int lane = t & 63;
  const int rowBase = (blockIdx.x * 4 + wave) * 32;
  const int l15 = lane & 15;
  const int quad = lane >> 4;
  const bool active = rowBase < N;

  // ---- stage Wl (coalesced 16B/thread) ----
#pragma unroll
  for (int it = 0; it < 8; it++) {
    int o = (it * 256 + t) * 8;
    *(s16x8*)&ws[o] = *(const s16x8*)&WlS[o];
  }

  // ---- aggregate this wave's 32 nodes into meanT ----
  if (active) {
    for (int nl = 0; nl < 32; nl++) {
      int node = rowBase + nl;
      if (node >= N) break;
      int o0 = offsets[node], o1 = offsets[node + 1];
      float acc[8];
#pragma unroll
      for (int i = 0; i < 8; i++) acc[i] = 0.f;
      int e = o0 + quad;
      for (; e + 4 < o1; e += 8) {
        int s0 = csr[e];
        int s1 = csr[e + 4];
        uint4 v0 = *(const uint4*)&hin[(size_t)s0 * HID + l15 * 8];
        uint4 v1 = *(const uint4*)&hin[(size_t)s1 * HID + l15 * 8];
        acc[0] += bfLo(v0.x) + bfLo(v1.x);
        acc[1] += bfHi(v0.x) + bfHi(v1.x);
        acc[2] += bfLo(v0.y) + bfLo(v1.y);
        acc[3] += bfHi(v0.y) + bfHi(v1.y);
        acc[4] += bfLo(v0.z) + bfLo(v1.z);
        acc[5] += bfHi(v0.z) + bfHi(v1.z);
        acc[6] += bfLo(v0.w) + bfLo(v1.w);
        acc[7] += bfHi(v0.w) + bfHi(v1.w);
      }
      if (e < o1) {
        int s0 = csr[e];
        uint4 v0 = *(const uint4*)&hin[(size_t)s0 * HID + l15 * 8];
        acc[0] += bfLo(v0.x); acc[1] += bfHi(v0.x);
        acc[2] += bfLo(v0.y); acc[3] += bfHi(v0.y);
        acc[4] += bfLo(v0.z); acc[5] += bfHi(v0.z);
        acc[6] += bfLo(v0.w); acc[7] += bfHi(v0.w);
      }
#pragma unroll
      for (int i = 0; i < 8; i++) {
        acc[i] += __shfl_xor(acc[i], 16, 64);
        acc[i] += __shfl_xor(acc[i], 32, 64);
      }
      if (quad == 0) {
        int d = o1 - o0;
        float inv = 1.0f / (float)(d > 1 ? d : 1);
        uint4 p;
        p.x = (uint_t)f2bf(acc[0] * inv) | ((uint_t)f2bf(acc[1] * inv) << 16);
        p.y = (uint_t)f2bf(acc[2] * inv) | ((uint_t)f2bf(acc[3] * inv) << 16);
        p.z = (uint_t)f2bf(acc[4] * inv) | ((uint_t)f2bf(acc[5] * inv) << 16);
        p.w = (uint_t)f2bf(acc[6] * inv) | ((uint_t)f2bf(acc[7] * inv) << 16);
        // chunk l15, XOR-swizzled by row
        *(uint4*)&meanT[((wave * 32 + nl) * 16 + (l15 ^ (nl & 7))) * 8] = p;
      }
    }
  }

  // ---- h A-frag prefetch (consumed phase 2; overlaps barrier + phase 1) ----
  s16x8 ah[2][4];
  if (active) {
    int r0 = rowBase + l15;       if (r0 >= N) r0 = N - 1;
    int r1 = rowBase + 16 + l15;  if (r1 >= N) r1 = N - 1;
#pragma unroll
    for (int ks = 0; ks < 4; ks++) {
      ah[0][ks] = *(const s16x8*)&hin[(size_t)r0 * HID + ks * 32 + quad * 8];
      ah[1][ks] = *(const s16x8*)&hin[(size_t)r1 * HID + ks * 32 + quad * 8];
    }
  }

  __syncthreads();  // Wl staged (meanT is wave-local but covered too)

  f32x4 acc[2][8];
#pragma unroll
  for (int mt = 0; mt < 2; mt++)
#pragma unroll
    for (int nt = 0; nt < 8; nt++) acc[mt][nt] = (f32x4){0.f, 0.f, 0.f, 0.f};

  // ---- phase 1: mean @ Wl (A from LDS, B from LDS) ----
  if (active) {
#pragma unroll
    for (int ks = 0; ks < 4; ks++) {
      int c = (ks * 4 + quad);
      s16x8 a0 = *(const s16x8*)&meanT[((wave * 32 + l15) * 16 + (c ^ (l15 & 7))) * 8];
      s16x8 a1 = *(const s16x8*)&meanT[((wave * 32 + 16 + l15) * 16 + (c ^ (l15 & 7))) * 8];
#pragma unroll
      for (int nt = 0; nt < 8; nt++) {
        s16x8 b = *(const s16x8*)&ws[((ks * 8 + nt) * 64 + lane) * 8];
        acc[0][nt] = __builtin_amdgcn_mfma_f32_16x16x32_bf16(a0, b, acc[0][nt], 0, 0, 0);
        acc[1][nt] = __builtin_amdgcn_mfma_f32_16x16x32_bf16(a1, b, acc[1][nt], 0, 0, 0);
      }
    }
  }

  __syncthreads();  // all waves done reading Wl
  // ---- stage Wr ----
#pragma unroll
  for (int it = 0; it < 8; it++) {
    int o = (it * 256 + t) * 8;
    *(s16x8*)&ws[o] = *(const s16x8*)&WrS[o];
  }
  __syncthreads();

  // ---- phase 2: h @ Wr + epilogue ----
  if (active) {
#pragma unroll
    for (int ks = 0; ks < 4; ks++)
#pragma unroll
      for (int nt = 0; nt < 8; nt++) {
        s16x8 b = *(const s16x8*)&ws[((ks * 8 + nt) * 64 + lane) * 8];
        acc[0][nt] = __builtin_amdgcn_mfma_f32_16x16x32_bf16(ah[0][ks], b, acc[0][nt], 0, 0, 0);
        acc[1][nt] = __builtin_amdgcn_mfma_f32_16x16x32_bf16(ah[1][ks], b, acc[1][nt], 0, 0, 0);
      }

#pragma unroll
    for (int mt = 0; mt < 2; mt++) {
#pragma unroll
      for (int nt = 0; nt < 8; nt++) {
        int col = nt * 16 + l15;
        float bv = bias[col];
#pragma unroll
        for (int r = 0; r < 4; r++) {
          int row = rowBase + mt * 16 + quad * 4 + r;
          if (row < N) {
            float v = fmaxf(acc[mt][nt][r] + bv, 0.f);
            if (outIsBf16) outB[(size_t)row * HID + col] = f2bf(v);
            else           outF[(size_t)row * HID + col] = v;
          }
        }
      }
    }
  }
}

extern "C" void kernel_launch(void* const* d_in, const int* in_sizes, int n_in,
                              void* d_out, int out_size, void* d_ws, size_t ws_size,
                              hipStream_t stream) {
  const int* x = (const int*)d_in[0];
  const int* ei = (const int*)d_in[1];
  const float* emb = (const float*)d_in[2];
  const float* Wl1 = (const float*)d_in[3];
  const float* bl1 = (const float*)d_in[4];
  const float* Wr1 = (const float*)d_in[5];
  const float* Wl2 = (const float*)d_in[6];
  const float* bl2 = (const float*)d_in[7];
  const float* Wr2 = (const float*)d_in[8];
  float* out = (float*)d_out;

  const int N = in_sizes[0];
  const int E = in_sizes[1] / 2;
  const int* srcI = ei;
  const int* dstI = ei + E;

  // workspace layout
  char* p = (char*)d_ws;
  ushort_t* hb = (ushort_t*)p;    p += (size_t)N * HID * sizeof(ushort_t);
  ushort_t* h2 = (ushort_t*)p;    p += (size_t)N * HID * sizeof(ushort_t);
  ushort_t* wb = (ushort_t*)p;    p += (size_t)4 * 16384 * sizeof(ushort_t);
  int* deg = (int*)p;             p += (size_t)((N + 3) & ~3) * sizeof(int);
  int* offsets = (int*)p;         p += (size_t)((N + 4) & ~3) * sizeof(int);
  int* cursor = (int*)p;          p += (size_t)((N + 3) & ~3) * sizeof(int);
  int* csr = (int*)p;             p += (size_t)((E + 3) & ~3) * sizeof(int);
  int* sums = (int*)p;            p += 256 * sizeof(int);

  ushort_t* Wlb1 = wb;
  ushort_t* Wrb1 = wb + 16384;
  ushort_t* Wlb2 = wb + 32768;
  ushort_t* Wrb2 = wb + 49152;

  const int nScanBlocks = (N + 1023) / 1024;  // <=256 required
  const int eBlocks = (E + 255) / 256;
  const int layerBlocks = (N + 127) / 128;
  const int prepBlocks = (N * 16 + 65536 + E + 255) / 256;

  // ---- CSR build + conversions ----
  hipMemsetAsync(deg, 0, (size_t)N * sizeof(int), stream);
  prep_kernel<<<prepBlocks, 256, 0, stream>>>(emb, x, hb, N,
                                              Wl1, Wr1, Wl2, Wr2, wb,
                                              dstI, deg, E);
  scan1_kernel<<<nScanBlocks, 256, 0, stream>>>(deg, offsets, sums, N);
  scan3_kernel<<<(N + 256) / 256, 256, 0, stream>>>(offsets, sums, cursor,
                                                    N, E, nScanBlocks);
  fill_kernel<<<eBlocks, 256, 0, stream>>>(srcI, dstI, cursor, csr, E);

  // ---- layer 1: hb -> h2 (bf16) ----
  fused_layer_kernel<<<layerBlocks, 256, 0, stream>>>(
      hb, offsets, csr, Wlb1, Wrb1, bl1, nullptr, h2, N, 1);

  // ---- layer 2: h2 -> out (f32) ----
  fused_layer_kernel<<<layerBlocks, 256, 0, stream>>>(
      h2, offsets, csr, Wlb2, Wrb2, bl2, out, nullptr, N, 0);
}

// Round 9
// 294.258 us; speedup vs baseline: 1.4766x; 1.4766x over previous
//
#include <hip/hip_runtime.h>

#define HID 128

typedef unsigned short ushort_t;
typedef unsigned int uint_t;
typedef float f32x4 __attribute__((ext_vector_type(4)));
typedef short s16x8 __attribute__((ext_vector_type(8)));

__device__ __forceinline__ ushort_t f2bf(float f) {
  uint_t u = __float_as_uint(f);
  uint_t r = (u + 0x7FFFu + ((u >> 16) & 1u)) >> 16;  // RNE
  return (ushort_t)r;
}
__device__ __forceinline__ float bfLo(uint_t v) { return __uint_as_float(v << 16); }
__device__ __forceinline__ float bfHi(uint_t v) { return __uint_as_float(v & 0xFFFF0000u); }

// ------- fused prep: wide gather + weight-swizzle + degree count -------
// Ranges: [0, N*16) gather (16 thr/row, 2 indep float4 loads + uint4 store);
// [N*16, +65536) weight swizzle to MFMA B-frag order; then E degcount.
__global__ __launch_bounds__(256) void prep_kernel(
    const float* __restrict__ emb, const int* __restrict__ x,
    ushort_t* __restrict__ hb, int N,
    const float* __restrict__ Wl1, const float* __restrict__ Wr1,
    const float* __restrict__ Wl2, const float* __restrict__ Wr2,
    ushort_t* __restrict__ wsw,
    const int* __restrict__ dst, int* __restrict__ deg, int E) {
  int tid = blockIdx.x * 256 + threadIdx.x;
  int gthreads = N * 16;
  if (tid < gthreads) {
    int r = tid >> 4, j = (tid & 15) * 8;
    int s = x[r];
    const float* src = &emb[(size_t)s * HID + j];
    float4 v0 = *(const float4*)src;
    float4 v1 = *(const float4*)(src + 4);
    uint4 p;
    p.x = (uint_t)f2bf(v0.x) | ((uint_t)f2bf(v0.y) << 16);
    p.y = (uint_t)f2bf(v0.z) | ((uint_t)f2bf(v0.w) << 16);
    p.z = (uint_t)f2bf(v1.x) | ((uint_t)f2bf(v1.y) << 16);
    p.w = (uint_t)f2bf(v1.z) | ((uint_t)f2bf(v1.w) << 16);
    *(uint4*)&hb[(size_t)r * HID + j] = p;
    return;
  }
  tid -= gthreads;
  if (tid < 65536) {
    const float* srcs[4] = {Wl1, Wr1, Wl2, Wr2};
    int m = tid >> 14, idx = tid & 16383;
    int j = idx & 7;
    int lane = (idx >> 3) & 63;
    int nt = (idx >> 9) & 7;
    int ks = (idx >> 12) & 3;
    int row = nt * 16 + (lane & 15);
    int col = ks * 32 + (lane >> 4) * 8 + j;
    wsw[tid] = f2bf(srcs[m][row * HID + col]);
    return;
  }
  tid -= 65536;
  if (tid < E) atomicAdd(&deg[dst[tid]], 1);
}

// ---------------- CSR build ----------------
__global__ __launch_bounds__(256) void scan1_kernel(
    const int* __restrict__ deg, int* __restrict__ offsets,
    int* __restrict__ sums, int N) {
  __shared__ int s[256];
  int b = blockIdx.x, t = threadIdx.x;
  int base = b * 1024 + t * 4;
  int v0 = 0, v1 = 0, v2 = 0, v3 = 0;
  if (base + 0 < N) v0 = deg[base + 0];
  if (base + 1 < N) v1 = deg[base + 1];
  if (base + 2 < N) v2 = deg[base + 2];
  if (base + 3 < N) v3 = deg[base + 3];
  int mySum = v0 + v1 + v2 + v3;
  s[t] = mySum;
  __syncthreads();
  for (int off = 1; off < 256; off <<= 1) {
    int v = (t >= off) ? s[t - off] : 0;
    __syncthreads();
    s[t] += v;
    __syncthreads();
  }
  int excl = s[t] - mySum;
  if (t == 255) sums[b] = s[255];
  if (base + 0 < N) offsets[base + 0] = excl;
  if (base + 1 < N) offsets[base + 1] = excl + v0;
  if (base + 2 < N) offsets[base + 2] = excl + v0 + v1;
  if (base + 3 < N) offsets[base + 3] = excl + v0 + v1 + v2;
}

__global__ __launch_bounds__(256) void scan3_kernel(
    int* __restrict__ offsets, const int* __restrict__ sums,
    int* __restrict__ cursor, int N, int E, int nb) {
  __shared__ int red[256];
  int t = threadIdx.x;
  int chunk = (blockIdx.x * 256) >> 10;
  red[t] = (t < chunk) ? sums[t] : 0;
  __syncthreads();
  for (int off = 128; off > 0; off >>= 1) {
    if (t < off) red[t] += red[t + off];
    __syncthreads();
  }
  int prefix = red[0];
  int i = blockIdx.x * 256 + t;
  if (i < N) {
    int v = offsets[i] + prefix;
    offsets[i] = v;
    cursor[i] = v;
  } else if (i == N) {
    offsets[N] = E;
  }
}

__global__ __launch_bounds__(256) void fill_kernel(
    const int* __restrict__ src, const int* __restrict__ dst,
    int* __restrict__ cursor, int* __restrict__ csr, int E) {
  int e = blockIdx.x * 256 + threadIdx.x;
  if (e >= E) return;
  int d = dst[e];
  int pos = atomicAdd(&cursor[d], 1);
  csr[pos] = src[e];
}

// ---------------- aggregate: one node per QUARTER-wave ----------------
// 16 lanes own a full 128-feat row (uint4 = 8 bf16/lane). Lane accumulates
// its 8 feats in f32 over the node's edges (2-batched -> 2 rows in flight
// per quad, 8 per wave). No cross-lane reduce, all 64 lanes write.
// (R8 lesson: keep one-node-per-quarter TLP; R5->R9 delta: halve per-wave
// instruction count by dropping the 16 ds_bpermute reduce + 1/4-width write.)
__global__ __launch_bounds__(256) void aggregate_kernel(
    const ushort_t* __restrict__ hb, const int* __restrict__ offsets,
    const int* __restrict__ csr, ushort_t* __restrict__ meanb, int N) {
  int t = threadIdx.x;
  int node = blockIdx.x * 16 + (t >> 4);
  if (node >= N) return;
  int l15 = t & 15;
  int o0 = offsets[node], o1 = offsets[node + 1];

  float acc[8];
#pragma unroll
  for (int i = 0; i < 8; i++) acc[i] = 0.f;

  int e = o0;
  for (; e + 1 < o1; e += 2) {
    int s0 = csr[e];
    int s1 = csr[e + 1];
    uint4 v0 = *(const uint4*)&hb[(size_t)s0 * HID + l15 * 8];
    uint4 v1 = *(const uint4*)&hb[(size_t)s1 * HID + l15 * 8];
    acc[0] += bfLo(v0.x) + bfLo(v1.x);
    acc[1] += bfHi(v0.x) + bfHi(v1.x);
    acc[2] += bfLo(v0.y) + bfLo(v1.y);
    acc[3] += bfHi(v0.y) + bfHi(v1.y);
    acc[4] += bfLo(v0.z) + bfLo(v1.z);
    acc[5] += bfHi(v0.z) + bfHi(v1.z);
    acc[6] += bfLo(v0.w) + bfLo(v1.w);
    acc[7] += bfHi(v0.w) + bfHi(v1.w);
  }
  if (e < o1) {
    int s0 = csr[e];
    uint4 v0 = *(const uint4*)&hb[(size_t)s0 * HID + l15 * 8];
    acc[0] += bfLo(v0.x); acc[1] += bfHi(v0.x);
    acc[2] += bfLo(v0.y); acc[3] += bfHi(v0.y);
    acc[4] += bfLo(v0.z); acc[5] += bfHi(v0.z);
    acc[6] += bfLo(v0.w); acc[7] += bfHi(v0.w);
  }

  int d = o1 - o0;
  float inv = 1.0f / (float)(d > 1 ? d : 1);
  uint4 p;
  p.x = (uint_t)f2bf(acc[0] * inv) | ((uint_t)f2bf(acc[1] * inv) << 16);
  p.y = (uint_t)f2bf(acc[2] * inv) | ((uint_t)f2bf(acc[3] * inv) << 16);
  p.z = (uint_t)f2bf(acc[4] * inv) | ((uint_t)f2bf(acc[5] * inv) << 16);
  p.w = (uint_t)f2bf(acc[6] * inv) | ((uint_t)f2bf(acc[7] * inv) << 16);
  *(uint4*)&meanb[(size_t)node * HID + l15 * 8] = p;
}

// ---------------- MFMA GEMM (R7, known-good): out = relu(mean@Wl^T + h@Wr^T + b) ----------------
// Weights (pre-swizzled to B-frag order) staged in LDS: 64 KB/block.
__global__ __launch_bounds__(256) void mfma_gemm_kernel(
    const ushort_t* __restrict__ meanb, const ushort_t* __restrict__ hb,
    const ushort_t* __restrict__ WlS, const ushort_t* __restrict__ WrS,
    const float* __restrict__ bias, float* __restrict__ outF,
    ushort_t* __restrict__ outB, int N, int outIsBf16) {
  __shared__ ushort_t ws[32768];  // 64 KB: [0..16383]=Wl frags, rest = Wr
  const int t = threadIdx.x;
  const int wave = t >> 6;
  const int lane = t & 63;
  const int rowBase = (blockIdx.x * 4 + wave) * 32;
  const int l15 = lane & 15;
  const int quad = lane >> 4;
  const int kq = quad * 8;
  const bool active = rowBase < N;

  int r0 = rowBase + l15;       if (r0 >= N) r0 = N - 1;
  int r1 = rowBase + 16 + l15;  if (r1 >= N) r1 = N - 1;

  // A-frag prefetch (independent of LDS staging)
  s16x8 a[2][2][4];  // [half][rowgrp][ks]
  if (active) {
#pragma unroll
    for (int ks = 0; ks < 4; ks++) {
      a[0][0][ks] = *(const s16x8*)&meanb[(size_t)r0 * HID + ks * 32 + kq];
      a[0][1][ks] = *(const s16x8*)&meanb[(size_t)r1 * HID + ks * 32 + kq];
      a[1][0][ks] = *(const s16x8*)&hb[(size_t)r0 * HID + ks * 32 + kq];
      a[1][1][ks] = *(const s16x8*)&hb[(size_t)r1 * HID + ks * 32 + kq];
    }
  }

  // stage both weight matrices: contiguous 16B per thread, coalesced
#pragma unroll
  for (int it = 0; it < 8; it++) {
    int o = (it * 256 + t) * 8;
    *(s16x8*)&ws[o] = *(const s16x8*)&WlS[o];
    *(s16x8*)&ws[16384 + o] = *(const s16x8*)&WrS[o];
  }
  __syncthreads();

  if (active) {
    f32x4 acc[2][8];
#pragma unroll
    for (int mt = 0; mt < 2; mt++)
#pragma unroll
      for (int nt = 0; nt < 8; nt++) acc[mt][nt] = (f32x4){0.f, 0.f, 0.f, 0.f};

#pragma unroll
    for (int half = 0; half < 2; half++) {
      const int hbase = half * 16384;
#pragma unroll
      for (int ks = 0; ks < 4; ks++)
#pragma unroll
        for (int nt = 0; nt < 8; nt++) {
          s16x8 b = *(const s16x8*)&ws[hbase + ((ks * 8 + nt) * 64 + lane) * 8];
          acc[0][nt] = __builtin_amdgcn_mfma_f32_16x16x32_bf16(a[half][0][ks], b, acc[0][nt], 0, 0, 0);
          acc[1][nt] = __builtin_amdgcn_mfma_f32_16x16x32_bf16(a[half][1][ks], b, acc[1][nt], 0, 0, 0);
        }
    }

#pragma unroll
    for (int mt = 0; mt < 2; mt++) {
#pragma unroll
      for (int nt = 0; nt < 8; nt++) {
        int col = nt * 16 + l15;
        float bv = bias[col];
#pragma unroll
        for (int r = 0; r < 4; r++) {
          int row = rowBase + mt * 16 + quad * 4 + r;
          if (row < N) {
            float v = fmaxf(acc[mt][nt][r] + bv, 0.f);
            if (outIsBf16) outB[(size_t)row * HID + col] = f2bf(v);
            else           outF[(size_t)row * HID + col] = v;
          }
        }
      }
    }
  }
}

extern "C" void kernel_launch(void* const* d_in, const int* in_sizes, int n_in,
                              void* d_out, int out_size, void* d_ws, size_t ws_size,
                              hipStream_t stream) {
  const int* x = (const int*)d_in[0];
  const int* ei = (const int*)d_in[1];
  const float* emb = (const float*)d_in[2];
  const float* Wl1 = (const float*)d_in[3];
  const float* bl1 = (const float*)d_in[4];
  const float* Wr1 = (const float*)d_in[5];
  const float* Wl2 = (const float*)d_in[6];
  const float* bl2 = (const float*)d_in[7];
  const float* Wr2 = (const float*)d_in[8];
  float* out = (float*)d_out;

  const int N = in_sizes[0];
  const int E = in_sizes[1] / 2;
  const int* srcI = ei;
  const int* dstI = ei + E;

  // workspace layout
  char* p = (char*)d_ws;
  ushort_t* hb = (ushort_t*)p;    p += (size_t)N * HID * sizeof(ushort_t);
  ushort_t* meanb = (ushort_t*)p; p += (size_t)N * HID * sizeof(ushort_t);
  ushort_t* wb = (ushort_t*)p;    p += (size_t)4 * 16384 * sizeof(ushort_t);
  int* deg = (int*)p;             p += (size_t)((N + 3) & ~3) * sizeof(int);
  int* offsets = (int*)p;         p += (size_t)((N + 4) & ~3) * sizeof(int);
  int* cursor = (int*)p;          p += (size_t)((N + 3) & ~3) * sizeof(int);
  int* csr = (int*)p;             p += (size_t)((E + 3) & ~3) * sizeof(int);
  int* sums = (int*)p;            p += 256 * sizeof(int);

  ushort_t* Wlb1 = wb;
  ushort_t* Wrb1 = wb + 16384;
  ushort_t* Wlb2 = wb + 32768;
  ushort_t* Wrb2 = wb + 49152;

  const int nScanBlocks = (N + 1023) / 1024;  // <=256 required
  const int eBlocks = (E + 255) / 256;
  const int gemmBlocks = (N + 127) / 128;
  const int aggBlocks = (N + 15) / 16;
  const int prepBlocks = (N * 16 + 65536 + E + 255) / 256;

  // ---- CSR build + conversions ----
  hipMemsetAsync(deg, 0, (size_t)N * sizeof(int), stream);
  prep_kernel<<<prepBlocks, 256, 0, stream>>>(emb, x, hb, N,
                                              Wl1, Wr1, Wl2, Wr2, wb,
                                              dstI, deg, E);
  scan1_kernel<<<nScanBlocks, 256, 0, stream>>>(deg, offsets, sums, N);
  scan3_kernel<<<(N + 256) / 256, 256, 0, stream>>>(offsets, sums, cursor,
                                                    N, E, nScanBlocks);
  fill_kernel<<<eBlocks, 256, 0, stream>>>(srcI, dstI, cursor, csr, E);

  // ---- layer 1 (gemm writes hb in place: waves touch only their own rows) ----
  aggregate_kernel<<<aggBlocks, 256, 0, stream>>>(hb, offsets, csr, meanb, N);
  mfma_gemm_kernel<<<gemmBlocks, 256, 0, stream>>>(meanb, hb, Wlb1, Wrb1, bl1,
                                                   nullptr, hb, N, 1);

  // ---- layer 2 ----
  aggregate_kernel<<<aggBlocks, 256, 0, stream>>>(hb, offsets, csr, meanb, N);
  mfma_gemm_kernel<<<gemmBlocks, 256, 0, stream>>>(meanb, hb, Wlb2, Wrb2, bl2,
                                                   out, nullptr, N, 0);
}

// Round 10
// 293.045 us; speedup vs baseline: 1.4827x; 1.0041x over previous
//
#include <hip/hip_runtime.h>

#define HID 128

typedef unsigned short ushort_t;
typedef unsigned int uint_t;
typedef float f32x4 __attribute__((ext_vector_type(4)));
typedef short s16x8 __attribute__((ext_vector_type(8)));

__device__ __forceinline__ ushort_t f2bf(float f) {
  uint_t u = __float_as_uint(f);
  uint_t r = (u + 0x7FFFu + ((u >> 16) & 1u)) >> 16;  // RNE
  return (ushort_t)r;
}
__device__ __forceinline__ float bfLo(uint_t v) { return __uint_as_float(v << 16); }
__device__ __forceinline__ float bfHi(uint_t v) { return __uint_as_float(v & 0xFFFF0000u); }

// ------- fused prep: 2-row gather + weight-swizzle + degree count -------
// Gather: each thread handles rows r and r+ceil(N/2) -> 2 indep x loads +
// 4 indep float4 emb loads in flight (R9: single-row version stuck at 43us,
// VALUBusy 3.7% = dependency-latency-bound).
// Ranges: [0, ceil(N/2)*16) gather; [+65536) weight swizzle; then E degcount.
__global__ __launch_bounds__(256) void prep_kernel(
    const float* __restrict__ emb, const int* __restrict__ x,
    ushort_t* __restrict__ hb, int N,
    const float* __restrict__ Wl1, const float* __restrict__ Wr1,
    const float* __restrict__ Wl2, const float* __restrict__ Wr2,
    ushort_t* __restrict__ wsw,
    const int* __restrict__ dst, int* __restrict__ deg, int E) {
  int tid = blockIdx.x * 256 + threadIdx.x;
  const int halfN = (N + 1) >> 1;
  int gthreads = halfN * 16;
  if (tid < gthreads) {
    int r0 = tid >> 4, j = (tid & 15) * 8;
    int r1 = r0 + halfN;
    int s0 = x[r0];
    int s1 = (r1 < N) ? x[r1] : s0;
    const float* src0 = &emb[(size_t)s0 * HID + j];
    const float* src1 = &emb[(size_t)s1 * HID + j];
    float4 a0 = *(const float4*)src0;
    float4 a1 = *(const float4*)(src0 + 4);
    float4 b0 = *(const float4*)src1;
    float4 b1 = *(const float4*)(src1 + 4);
    uint4 p;
    p.x = (uint_t)f2bf(a0.x) | ((uint_t)f2bf(a0.y) << 16);
    p.y = (uint_t)f2bf(a0.z) | ((uint_t)f2bf(a0.w) << 16);
    p.z = (uint_t)f2bf(a1.x) | ((uint_t)f2bf(a1.y) << 16);
    p.w = (uint_t)f2bf(a1.z) | ((uint_t)f2bf(a1.w) << 16);
    *(uint4*)&hb[(size_t)r0 * HID + j] = p;
    if (r1 < N) {
      uint4 q;
      q.x = (uint_t)f2bf(b0.x) | ((uint_t)f2bf(b0.y) << 16);
      q.y = (uint_t)f2bf(b0.z) | ((uint_t)f2bf(b0.w) << 16);
      q.z = (uint_t)f2bf(b1.x) | ((uint_t)f2bf(b1.y) << 16);
      q.w = (uint_t)f2bf(b1.z) | ((uint_t)f2bf(b1.w) << 16);
      *(uint4*)&hb[(size_t)r1 * HID + j] = q;
    }
    return;
  }
  tid -= gthreads;
  if (tid < 65536) {
    const float* srcs[4] = {Wl1, Wr1, Wl2, Wr2};
    int m = tid >> 14, idx = tid & 16383;
    int j = idx & 7;
    int lane = (idx >> 3) & 63;
    int nt = (idx >> 9) & 7;
    int ks = (idx >> 12) & 3;
    int row = nt * 16 + (lane & 15);
    int col = ks * 32 + (lane >> 4) * 8 + j;
    wsw[tid] = f2bf(srcs[m][row * HID + col]);
    return;
  }
  tid -= 65536;
  if (tid < E) atomicAdd(&deg[dst[tid]], 1);
}

// ---------------- CSR build ----------------
__global__ __launch_bounds__(256) void scan1_kernel(
    const int* __restrict__ deg, int* __restrict__ offsets,
    int* __restrict__ sums, int N) {
  __shared__ int s[256];
  int b = blockIdx.x, t = threadIdx.x;
  int base = b * 1024 + t * 4;
  int v0 = 0, v1 = 0, v2 = 0, v3 = 0;
  if (base + 0 < N) v0 = deg[base + 0];
  if (base + 1 < N) v1 = deg[base + 1];
  if (base + 2 < N) v2 = deg[base + 2];
  if (base + 3 < N) v3 = deg[base + 3];
  int mySum = v0 + v1 + v2 + v3;
  s[t] = mySum;
  __syncthreads();
  for (int off = 1; off < 256; off <<= 1) {
    int v = (t >= off) ? s[t - off] : 0;
    __syncthreads();
    s[t] += v;
    __syncthreads();
  }
  int excl = s[t] - mySum;
  if (t == 255) sums[b] = s[255];
  if (base + 0 < N) offsets[base + 0] = excl;
  if (base + 1 < N) offsets[base + 1] = excl + v0;
  if (base + 2 < N) offsets[base + 2] = excl + v0 + v1;
  if (base + 3 < N) offsets[base + 3] = excl + v0 + v1 + v2;
}

__global__ __launch_bounds__(256) void scan3_kernel(
    int* __restrict__ offsets, const int* __restrict__ sums,
    int* __restrict__ cursor, int N, int E, int nb) {
  __shared__ int red[256];
  int t = threadIdx.x;
  int chunk = (blockIdx.x * 256) >> 10;
  red[t] = (t < chunk) ? sums[t] : 0;
  __syncthreads();
  for (int off = 128; off > 0; off >>= 1) {
    if (t < off) red[t] += red[t + off];
    __syncthreads();
  }
  int prefix = red[0];
  int i = blockIdx.x * 256 + t;
  if (i < N) {
    int v = offsets[i] + prefix;
    offsets[i] = v;
    cursor[i] = v;
  } else if (i == N) {
    offsets[N] = E;
  }
}

__global__ __launch_bounds__(256) void fill_kernel(
    const int* __restrict__ src, const int* __restrict__ dst,
    int* __restrict__ cursor, int* __restrict__ csr, int E) {
  int e = blockIdx.x * 256 + threadIdx.x;
  if (e >= E) return;
  int d = dst[e];
  int pos = atomicAdd(&cursor[d], 1);
  csr[pos] = src[e];
}

// ---------------- aggregate: one node per QUARTER-wave, 4-deep batch ----------------
// 16 lanes own a full 128-feat row (uint4 = 8 bf16/lane). 4->2->1 edge
// batching: mean degree 6 takes 2 load-rounds (was 3 with 2-deep).
__global__ __launch_bounds__(256) void aggregate_kernel(
    const ushort_t* __restrict__ hb, const int* __restrict__ offsets,
    const int* __restrict__ csr, ushort_t* __restrict__ meanb, int N) {
  int t = threadIdx.x;
  int node = blockIdx.x * 16 + (t >> 4);
  if (node >= N) return;
  int l15 = t & 15;
  int o0 = offsets[node], o1 = offsets[node + 1];

  float acc[8];
#pragma unroll
  for (int i = 0; i < 8; i++) acc[i] = 0.f;

  int e = o0;
  for (; e + 3 < o1; e += 4) {
    int s0 = csr[e], s1 = csr[e + 1], s2 = csr[e + 2], s3 = csr[e + 3];
    uint4 v0 = *(const uint4*)&hb[(size_t)s0 * HID + l15 * 8];
    uint4 v1 = *(const uint4*)&hb[(size_t)s1 * HID + l15 * 8];
    uint4 v2 = *(const uint4*)&hb[(size_t)s2 * HID + l15 * 8];
    uint4 v3 = *(const uint4*)&hb[(size_t)s3 * HID + l15 * 8];
    acc[0] += (bfLo(v0.x) + bfLo(v1.x)) + (bfLo(v2.x) + bfLo(v3.x));
    acc[1] += (bfHi(v0.x) + bfHi(v1.x)) + (bfHi(v2.x) + bfHi(v3.x));
    acc[2] += (bfLo(v0.y) + bfLo(v1.y)) + (bfLo(v2.y) + bfLo(v3.y));
    acc[3] += (bfHi(v0.y) + bfHi(v1.y)) + (bfHi(v2.y) + bfHi(v3.y));
    acc[4] += (bfLo(v0.z) + bfLo(v1.z)) + (bfLo(v2.z) + bfLo(v3.z));
    acc[5] += (bfHi(v0.z) + bfHi(v1.z)) + (bfHi(v2.z) + bfHi(v3.z));
    acc[6] += (bfLo(v0.w) + bfLo(v1.w)) + (bfLo(v2.w) + bfLo(v3.w));
    acc[7] += (bfHi(v0.w) + bfHi(v1.w)) + (bfHi(v2.w) + bfHi(v3.w));
  }
  if (e + 1 < o1) {
    int s0 = csr[e], s1 = csr[e + 1];
    uint4 v0 = *(const uint4*)&hb[(size_t)s0 * HID + l15 * 8];
    uint4 v1 = *(const uint4*)&hb[(size_t)s1 * HID + l15 * 8];
    acc[0] += bfLo(v0.x) + bfLo(v1.x);
    acc[1] += bfHi(v0.x) + bfHi(v1.x);
    acc[2] += bfLo(v0.y) + bfLo(v1.y);
    acc[3] += bfHi(v0.y) + bfHi(v1.y);
    acc[4] += bfLo(v0.z) + bfLo(v1.z);
    acc[5] += bfHi(v0.z) + bfHi(v1.z);
    acc[6] += bfLo(v0.w) + bfLo(v1.w);
    acc[7] += bfHi(v0.w) + bfHi(v1.w);
    e += 2;
  }
  if (e < o1) {
    int s0 = csr[e];
    uint4 v0 = *(const uint4*)&hb[(size_t)s0 * HID + l15 * 8];
    acc[0] += bfLo(v0.x); acc[1] += bfHi(v0.x);
    acc[2] += bfLo(v0.y); acc[3] += bfHi(v0.y);
    acc[4] += bfLo(v0.z); acc[5] += bfHi(v0.z);
    acc[6] += bfLo(v0.w); acc[7] += bfHi(v0.w);
  }

  int d = o1 - o0;
  float inv = 1.0f / (float)(d > 1 ? d : 1);
  uint4 p;
  p.x = (uint_t)f2bf(acc[0] * inv) | ((uint_t)f2bf(acc[1] * inv) << 16);
  p.y = (uint_t)f2bf(acc[2] * inv) | ((uint_t)f2bf(acc[3] * inv) << 16);
  p.z = (uint_t)f2bf(acc[4] * inv) | ((uint_t)f2bf(acc[5] * inv) << 16);
  p.w = (uint_t)f2bf(acc[6] * inv) | ((uint_t)f2bf(acc[7] * inv) << 16);
  *(uint4*)&meanb[(size_t)node * HID + l15 * 8] = p;
}

// ---------------- MFMA GEMM (R7, known-good): out = relu(mean@Wl^T + h@Wr^T + b) ----------------
// Weights (pre-swizzled to B-frag order) staged in LDS: 64 KB/block.
__global__ __launch_bounds__(256) void mfma_gemm_kernel(
    const ushort_t* __restrict__ meanb, const ushort_t* __restrict__ hb,
    const ushort_t* __restrict__ WlS, const ushort_t* __restrict__ WrS,
    const float* __restrict__ bias, float* __restrict__ outF,
    ushort_t* __restrict__ outB, int N, int outIsBf16) {
  __shared__ ushort_t ws[32768];  // 64 KB: [0..16383]=Wl frags, rest = Wr
  const int t = threadIdx.x;
  const int wave = t >> 6;
  const int lane = t & 63;
  const int rowBase = (blockIdx.x * 4 + wave) * 32;
  const int l15 = lane & 15;
  const int quad = lane >> 4;
  const int kq = quad * 8;
  const bool active = rowBase < N;

  int r0 = rowBase + l15;       if (r0 >= N) r0 = N - 1;
  int r1 = rowBase + 16 + l15;  if (r1 >= N) r1 = N - 1;

  // A-frag prefetch (independent of LDS staging)
  s16x8 a[2][2][4];  // [half][rowgrp][ks]
  if (active) {
#pragma unroll
    for (int ks = 0; ks < 4; ks++) {
      a[0][0][ks] = *(const s16x8*)&meanb[(size_t)r0 * HID + ks * 32 + kq];
      a[0][1][ks] = *(const s16x8*)&meanb[(size_t)r1 * HID + ks * 32 + kq];
      a[1][0][ks] = *(const s16x8*)&hb[(size_t)r0 * HID + ks * 32 + kq];
      a[1][1][ks] = *(const s16x8*)&hb[(size_t)r1 * HID + ks * 32 + kq];
    }
  }

  // stage both weight matrices: contiguous 16B per thread, coalesced
#pragma unroll
  for (int it = 0; it < 8; it++) {
    int o = (it * 256 + t) * 8;
    *(s16x8*)&ws[o] = *(const s16x8*)&WlS[o];
    *(s16x8*)&ws[16384 + o] = *(const s16x8*)&WrS[o];
  }
  __syncthreads();

  if (active) {
    f32x4 acc[2][8];
#pragma unroll
    for (int mt = 0; mt < 2; mt++)
#pragma unroll
      for (int nt = 0; nt < 8; nt++) acc[mt][nt] = (f32x4){0.f, 0.f, 0.f, 0.f};

#pragma unroll
    for (int half = 0; half < 2; half++) {
      const int hbase = half * 16384;
#pragma unroll
      for (int ks = 0; ks < 4; ks++)
#pragma unroll
        for (int nt = 0; nt < 8; nt++) {
          s16x8 b = *(const s16x8*)&ws[hbase + ((ks * 8 + nt) * 64 + lane) * 8];
          acc[0][nt] = __builtin_amdgcn_mfma_f32_16x16x32_bf16(a[half][0][ks], b, acc[0][nt], 0, 0, 0);
          acc[1][nt] = __builtin_amdgcn_mfma_f32_16x16x32_bf16(a[half][1][ks], b, acc[1][nt], 0, 0, 0);
        }
    }

#pragma unroll
    for (int mt = 0; mt < 2; mt++) {
#pragma unroll
      for (int nt = 0; nt < 8; nt++) {
        int col = nt * 16 + l15;
        float bv = bias[col];
#pragma unroll
        for (int r = 0; r < 4; r++) {
          int row = rowBase + mt * 16 + quad * 4 + r;
          if (row < N) {
            float v = fmaxf(acc[mt][nt][r] + bv, 0.f);
            if (outIsBf16) outB[(size_t)row * HID + col] = f2bf(v);
            else           outF[(size_t)row * HID + col] = v;
          }
        }
      }
    }
  }
}

extern "C" void kernel_launch(void* const* d_in, const int* in_sizes, int n_in,
                              void* d_out, int out_size, void* d_ws, size_t ws_size,
                              hipStream_t stream) {
  const int* x = (const int*)d_in[0];
  const int* ei = (const int*)d_in[1];
  const float* emb = (const float*)d_in[2];
  const float* Wl1 = (const float*)d_in[3];
  const float* bl1 = (const float*)d_in[4];
  const float* Wr1 = (const float*)d_in[5];
  const float* Wl2 = (const float*)d_in[6];
  const float* bl2 = (const float*)d_in[7];
  const float* Wr2 = (const float*)d_in[8];
  float* out = (float*)d_out;

  const int N = in_sizes[0];
  const int E = in_sizes[1] / 2;
  const int* srcI = ei;
  const int* dstI = ei + E;

  // workspace layout
  char* p = (char*)d_ws;
  ushort_t* hb = (ushort_t*)p;    p += (size_t)N * HID * sizeof(ushort_t);
  ushort_t* meanb = (ushort_t*)p; p += (size_t)N * HID * sizeof(ushort_t);
  ushort_t* wb = (ushort_t*)p;    p += (size_t)4 * 16384 * sizeof(ushort_t);
  int* deg = (int*)p;             p += (size_t)((N + 3) & ~3) * sizeof(int);
  int* offsets = (int*)p;         p += (size_t)((N + 4) & ~3) * sizeof(int);
  int* cursor = (int*)p;          p += (size_t)((N + 3) & ~3) * sizeof(int);
  int* csr = (int*)p;             p += (size_t)((E + 3) & ~3) * sizeof(int);
  int* sums = (int*)p;            p += 256 * sizeof(int);

  ushort_t* Wlb1 = wb;
  ushort_t* Wrb1 = wb + 16384;
  ushort_t* Wlb2 = wb + 32768;
  ushort_t* Wrb2 = wb + 49152;

  const int nScanBlocks = (N + 1023) / 1024;  // <=256 required
  const int eBlocks = (E + 255) / 256;
  const int gemmBlocks = (N + 127) / 128;
  const int aggBlocks = (N + 15) / 16;
  const int halfN = (N + 1) / 2;
  const int prepBlocks = (halfN * 16 + 65536 + E + 255) / 256;

  // ---- CSR build + conversions ----
  hipMemsetAsync(deg, 0, (size_t)N * sizeof(int), stream);
  prep_kernel<<<prepBlocks, 256, 0, stream>>>(emb, x, hb, N,
                                              Wl1, Wr1, Wl2, Wr2, wb,
                                              dstI, deg, E);
  scan1_kernel<<<nScanBlocks, 256, 0, stream>>>(deg, offsets, sums, N);
  scan3_kernel<<<(N + 256) / 256, 256, 0, stream>>>(offsets, sums, cursor,
                                                    N, E, nScanBlocks);
  fill_kernel<<<eBlocks, 256, 0, stream>>>(srcI, dstI, cursor, csr, E);

  // ---- layer 1 (gemm writes hb in place: waves touch only their own rows) ----
  aggregate_kernel<<<aggBlocks, 256, 0, stream>>>(hb, offsets, csr, meanb, N);
  mfma_gemm_kernel<<<gemmBlocks, 256, 0, stream>>>(meanb, hb, Wlb1, Wrb1, bl1,
                                                   nullptr, hb, N, 1);

  // ---- layer 2 ----
  aggregate_kernel<<<aggBlocks, 256, 0, stream>>>(hb, offsets, csr, meanb, N);
  mfma_gemm_kernel<<<gemmBlocks, 256, 0, stream>>>(meanb, hb, Wlb2, Wrb2, bl2,
                                                   out, nullptr, N, 0);
}